// Round 1
// baseline (2883.193 us; speedup 1.0000x reference)
//
#include <hip/hip_runtime.h>
#include <math.h>

#define D_MODEL 768
#define HEADS   8
#define HDIM    96
#define SEQ     49
#define KQ      100
#define NB      128
#define FDIM    2048
#define FFD     2048
#define GRP     10
#define NCLS    1000

// ---------------------------------------------------------------------------
// Generic fp32 GEMM: C[M,N] = act((A@B + bias) * scale)
// A: M x Kd row-major (XMODE=1: A is x[B,F,7,7], row=(b,s), col=f)
// B: Kd x N row-major.  Requires N % 128 == 0, Kd % 8 == 0.
// 128x128 tile, BK=8, 256 threads, 8x8 per-thread microtile.
// ---------------------------------------------------------------------------
template <int XMODE>
__global__ __launch_bounds__(256) void gemm_f32(
    const float* __restrict__ A, const float* __restrict__ B,
    const float* __restrict__ bias, float* __restrict__ C,
    int M, int N, int Kd, int relu, float scale)
{
    __shared__ float As[8][132];
    __shared__ float Bs[8][132];

    const int tid = threadIdx.x;
    const int tx = tid & 15;         // 0..15 -> 8 cols each
    const int ty = tid >> 4;         // 0..15 -> 8 rows each
    const int rowBase = blockIdx.y * 128;
    const int nBase   = blockIdx.x * 128;

    float acc[8][8];
#pragma unroll
    for (int i = 0; i < 8; i++)
#pragma unroll
        for (int j = 0; j < 8; j++) acc[i][j] = 0.f;

    for (int k0 = 0; k0 < Kd; k0 += 8) {
        // Load A tile: 128 rows x 8 k
#pragma unroll
        for (int i = 0; i < 4; i++) {
            int l = tid + i * 256;
            int m = l >> 3, kk = l & 7;
            int row = rowBase + m;
            float vv = 0.f;
            if (XMODE) {
                // row = b*49+s ; elem = x[(b*FDIM + f)*49 + s]
                int b = row / SEQ, s = row - b * SEQ;
                vv = A[(b * FDIM + (k0 + kk)) * SEQ + s];
            } else {
                if (row < M) vv = A[row * Kd + k0 + kk];
            }
            As[kk][m] = vv;
        }
        // Load B tile: 8 k x 128 n (fully coalesced)
#pragma unroll
        for (int i = 0; i < 4; i++) {
            int l = tid + i * 256;
            int kk = l >> 7, n = l & 127;
            Bs[kk][n] = B[(k0 + kk) * N + nBase + n];
        }
        __syncthreads();

#pragma unroll
        for (int kk = 0; kk < 8; kk++) {
            float a[8], bb[8];
#pragma unroll
            for (int i = 0; i < 8; i++) a[i] = As[kk][ty * 8 + i];
#pragma unroll
            for (int j = 0; j < 8; j++) bb[j] = Bs[kk][tx * 8 + j];
#pragma unroll
            for (int i = 0; i < 8; i++)
#pragma unroll
                for (int j = 0; j < 8; j++)
                    acc[i][j] = fmaf(a[i], bb[j], acc[i][j]);
        }
        __syncthreads();
    }

#pragma unroll
    for (int i = 0; i < 8; i++) {
        int row = rowBase + ty * 8 + i;
        if (row < M) {
#pragma unroll
            for (int j = 0; j < 8; j++) {
                int col = nBase + tx * 8 + j;
                float v = (acc[i][j] + bias[col]) * scale;
                if (relu) v = fmaxf(v, 0.f);
                C[row * N + col] = v;
            }
        }
    }
}

// ---------------------------------------------------------------------------
// LayerNorm over D=768, one block (256 thr) per row.
// out = LN(pre_scale*in + resid) * g + be
// rmode: 0 none, 1 full residual, 2 broadcast residual (row % KQ)
// Safe in-place (each row touched by exactly one block, read->stats->write).
// ---------------------------------------------------------------------------
__device__ inline float block_reduce_sum_f(float v, float* red)
{
#pragma unroll
    for (int off = 32; off > 0; off >>= 1) v += __shfl_down(v, off);
    int lane = threadIdx.x & 63, w = threadIdx.x >> 6;
    if (lane == 0) red[w] = v;
    __syncthreads();
    float total = red[0] + red[1] + red[2] + red[3];
    __syncthreads();
    return total;
}

__global__ __launch_bounds__(256) void ln_f32(
    const float* __restrict__ in, const float* __restrict__ resid, int rmode,
    const float* __restrict__ g, const float* __restrict__ be,
    float* __restrict__ out, float pre_scale)
{
    __shared__ float red[4];
    const int row = blockIdx.x;
    const int tid = threadIdx.x;

    float v[3];
#pragma unroll
    for (int i = 0; i < 3; i++) {
        int d = tid + i * 256;
        float x = pre_scale * in[row * D_MODEL + d];
        if (rmode == 1)      x += resid[row * D_MODEL + d];
        else if (rmode == 2) x += resid[(row % KQ) * D_MODEL + d];
        v[i] = x;
    }
    float s = block_reduce_sum_f(v[0] + v[1] + v[2], red);
    float mean = s * (1.f / D_MODEL);
    float d0 = v[0] - mean, d1 = v[1] - mean, d2 = v[2] - mean;
    float sq = block_reduce_sum_f(d0 * d0 + d1 * d1 + d2 * d2, red);
    float rstd = rsqrtf(sq * (1.f / D_MODEL) + 1e-5f);
#pragma unroll
    for (int i = 0; i < 3; i++) {
        int d = tid + i * 256;
        out[row * D_MODEL + d] = (v[i] - mean) * rstd * g[d] + be[d];
    }
}

// ---------------------------------------------------------------------------
// Fused cross-attention per (b,h): scores -> softmax -> ctx.
// q is pre-scaled by 1/sqrt(HDIM). K/V slabs staged in LDS (stride 97: HDIM=96
// is 0 mod 32 banks -> would be fully conflicted otherwise).
// ---------------------------------------------------------------------------
__global__ __launch_bounds__(256) void attn_f32(
    const float* __restrict__ q, const float* __restrict__ k,
    const float* __restrict__ v, float* __restrict__ ctx)
{
    __shared__ float Ks[SEQ][HDIM + 1];
    __shared__ float Vs[SEQ][HDIM + 1];
    __shared__ float qs[HDIM];
    __shared__ float scs[SEQ];
    __shared__ float mred[2];

    const int bh = blockIdx.x;
    const int b = bh / HEADS, h = bh - b * HEADS;
    const int tid = threadIdx.x;

    for (int idx = tid; idx < SEQ * HDIM; idx += 256) {
        int s = idx / HDIM, dh = idx - s * HDIM;
        int ga = (b * SEQ + s) * D_MODEL + h * HDIM + dh;
        Ks[s][dh] = k[ga];
        Vs[s][dh] = v[ga];
    }
    __syncthreads();

    for (int kq = 0; kq < KQ; kq++) {
        if (tid < HDIM) qs[tid] = q[kq * D_MODEL + h * HDIM + tid];
        __syncthreads();
        if (tid < SEQ) {
            float a = 0.f;
#pragma unroll
            for (int dh = 0; dh < HDIM; dh++) a = fmaf(qs[dh], Ks[tid][dh], a);
            scs[tid] = a;
        }
        __syncthreads();
        if (tid == 0) {
            float mx = -1e30f;
            for (int s = 0; s < SEQ; s++) mx = fmaxf(mx, scs[s]);
            mred[0] = mx;
        }
        __syncthreads();
        if (tid < SEQ) scs[tid] = __expf(scs[tid] - mred[0]);
        __syncthreads();
        if (tid == 0) {
            float sm = 0.f;
            for (int s = 0; s < SEQ; s++) sm += scs[s];
            mred[1] = 1.f / sm;
        }
        __syncthreads();
        if (tid < HDIM) {
            float a = 0.f;
#pragma unroll
            for (int s = 0; s < SEQ; s++) a = fmaf(scs[s], Vs[s][tid], a);
            ctx[(b * KQ + kq) * D_MODEL + h * HDIM + tid] = a * mred[1];
        }
        __syncthreads();
    }
}

// ---------------------------------------------------------------------------
// GroupFC: logits[b, k*GRP+g] = h[b,k,:] . dup_pool[k,:,g] + dup_bias
// One block per (b,k); 4 waves cover the 10 groups.
// ---------------------------------------------------------------------------
__global__ __launch_bounds__(256) void groupfc_f32(
    const float* __restrict__ h, const float* __restrict__ dp,
    const float* __restrict__ dbias, float* __restrict__ out)
{
    __shared__ float hs[D_MODEL];
    const int bk = blockIdx.x;
    const int b = bk / KQ, kq = bk - b * KQ;
    const int tid = threadIdx.x;

#pragma unroll
    for (int i = 0; i < 3; i++)
        hs[tid + i * 256] = h[(b * KQ + kq) * D_MODEL + tid + i * 256];
    __syncthreads();

    const int w = tid >> 6, lane = tid & 63;
    for (int g = w; g < GRP; g += 4) {
        float a = 0.f;
#pragma unroll
        for (int i = 0; i < 12; i++) {
            int d = lane + i * 64;
            a = fmaf(hs[d], dp[(kq * D_MODEL + d) * GRP + g], a);
        }
#pragma unroll
        for (int off = 32; off > 0; off >>= 1) a += __shfl_down(a, off);
        if (lane == 0) out[b * NCLS + kq * GRP + g] = a + dbias[kq * GRP + g];
    }
}

// ---------------------------------------------------------------------------
extern "C" void kernel_launch(void* const* d_in, const int* in_sizes, int n_in,
                              void* d_out, int out_size, void* d_ws, size_t ws_size,
                              hipStream_t stream)
{
    const float* x   = (const float*)d_in[0];
    const float* We  = (const float*)d_in[1];
    const float* be_ = (const float*)d_in[2];
    const float* qe  = (const float*)d_in[3];
    const float* wq  = (const float*)d_in[4];
    const float* wk  = (const float*)d_in[5];
    const float* wv  = (const float*)d_in[6];
    const float* bq  = (const float*)d_in[7];
    const float* bk  = (const float*)d_in[8];
    const float* bv  = (const float*)d_in[9];
    const float* wo  = (const float*)d_in[10];
    const float* bo  = (const float*)d_in[11];
    const float* w1  = (const float*)d_in[12];
    const float* b1  = (const float*)d_in[13];
    const float* w2  = (const float*)d_in[14];
    const float* b2  = (const float*)d_in[15];
    const float* g1  = (const float*)d_in[16];
    const float* be1 = (const float*)d_in[17];
    const float* g2  = (const float*)d_in[18];
    const float* be2 = (const float*)d_in[19];
    const float* g3  = (const float*)d_in[20];
    const float* be3 = (const float*)d_in[21];
    const float* dp  = (const float*)d_in[22];
    const float* db  = (const float*)d_in[23];
    float* out = (float*)d_out;
    float* ws  = (float*)d_ws;

    // Workspace arena (floats). Region0 (26,214,400 fl = 105 MB) is time-shared:
    //   phase A: mem | k | v | ctx   (24.3M fl)   phase B: ff1 (26.2M fl)
    float* ffh = ws;                    // 12800*2048
    float* mem = ws;                    // 6272*768
    float* kb  = ws + 4816896;          // 6272*768
    float* vb  = ws + 9633792;          // 6272*768
    float* ctx = ws + 14450688;         // 12800*768
    float* tgt = ws + 26214400;         // 100*768
    float* qb  = tgt + 76800;           // 100*768
    float* t2  = qb + 76800;            // 12800*768 (attn_out -> tgt2 in place)
    float* hb  = t2 + 9830400;          // 12800*768 (ff2 -> h in place)
    // total: 46,028,800 floats = 184.1 MB

    dim3 blk(256);
    const float qscale = 1.0f / sqrtf((float)HDIM);

    // 1. mem = relu(x^T @ W_embed + b_embed)   [6272 x 768, K=2048]
    gemm_f32<1><<<dim3(6, 49), blk, 0, stream>>>(x, We, be_, mem, 6272, 768, 2048, 1, 1.f);
    // 2. tgt = LN(2*query_embed)               [100 x 768]
    ln_f32<<<dim3(KQ), blk, 0, stream>>>(qe, nullptr, 0, g1, be1, tgt, 2.0f);
    // 3. q = (tgt@wq + bq) / sqrt(96)          [100 x 768, K=768]
    gemm_f32<0><<<dim3(6, 1), blk, 0, stream>>>(tgt, wq, bq, qb, KQ, 768, 768, 0, qscale);
    // 4/5. k, v                                [6272 x 768, K=768]
    gemm_f32<0><<<dim3(6, 49), blk, 0, stream>>>(mem, wk, bk, kb, 6272, 768, 768, 0, 1.f);
    gemm_f32<0><<<dim3(6, 49), blk, 0, stream>>>(mem, wv, bv, vb, 6272, 768, 768, 0, 1.f);
    // 6. fused attention -> ctx                [B*H blocks]
    attn_f32<<<dim3(NB * HEADS), blk, 0, stream>>>(qb, kb, vb, ctx);
    // 7. attn_out = ctx@wo + bo -> t2          [12800 x 768, K=768]
    gemm_f32<0><<<dim3(6, 100), blk, 0, stream>>>(ctx, wo, bo, t2, 12800, 768, 768, 0, 1.f);
    // 8. t2 = LN(t2 + broadcast tgt)           in-place
    ln_f32<<<dim3(12800), blk, 0, stream>>>(t2, tgt, 2, g2, be2, t2, 1.0f);
    // 9. ffh = relu(t2@w1 + b1)                [12800 x 2048, K=768]
    gemm_f32<0><<<dim3(16, 100), blk, 0, stream>>>(t2, w1, b1, ffh, 12800, 2048, 768, 1, 1.f);
    // 10. hb = ffh@w2 + b2                     [12800 x 768, K=2048]
    gemm_f32<0><<<dim3(6, 100), blk, 0, stream>>>(ffh, w2, b2, hb, 12800, 768, 2048, 0, 1.f);
    // 11. hb = LN(hb + t2)                     in-place
    ln_f32<<<dim3(12800), blk, 0, stream>>>(hb, t2, 1, g3, be3, hb, 1.0f);
    // 12. GroupFC -> out
    groupfc_f32<<<dim3(12800), blk, 0, stream>>>(hb, dp, db, out);
}

// Round 2
// 812.360 us; speedup vs baseline: 3.5492x; 3.5492x over previous
//
#include <hip/hip_runtime.h>
#include <math.h>

#define D_MODEL 768
#define HEADS   8
#define HDIM    96
#define SEQ     49
#define KQ      100
#define NB      128
#define FDIM    2048
#define FFD     2048
#define GRP     10
#define NCLS    1000

typedef unsigned short ushort_t;
typedef unsigned int uint_t;
typedef __attribute__((ext_vector_type(8))) short short8;
typedef __attribute__((ext_vector_type(4))) float f32x4;

// ---------------------------------------------------------------------------
// bf16 helpers (RNE rounding)
// ---------------------------------------------------------------------------
__device__ __forceinline__ float bf2f(ushort_t u) {
    uint_t x = ((uint_t)u) << 16;
    return __uint_as_float(x);
}
__device__ __forceinline__ ushort_t f2bf(float f) {
    uint_t x = __float_as_uint(f);
    x += 0x7fffu + ((x >> 16) & 1u);
    return (ushort_t)(x >> 16);
}

// async global->LDS, 16 bytes per lane (lds dest = wave-uniform base + lane*16)
__device__ __forceinline__ void gld_lds16(const void* g, void* l) {
    __builtin_amdgcn_global_load_lds(
        (const __attribute__((address_space(1))) unsigned int*)g,
        (__attribute__((address_space(3))) unsigned int*)l, 16, 0, 0);
}

// ---------------------------------------------------------------------------
// bf16 MFMA GEMM (m97 structure): C[M,N] = act((A@B + bias)*scale), bf16 out.
// A: [M][K] bf16 row-major.  Bt: [N][K] bf16 row-major (B transposed).
// 128x128 tile, BK=32, 256 thr = 4 waves, each wave 64x64 (4x4 of 16x16x32).
// Requires K%32==0, N%128==0.  M masked (rows clamped on load, guarded store).
// ---------------------------------------------------------------------------
__global__ __launch_bounds__(256) void gemm_bf16(
    const ushort_t* __restrict__ A, const ushort_t* __restrict__ Bt,
    const float* __restrict__ bias, ushort_t* __restrict__ C,
    int M, int N, int K, int relu, float scale)
{
    __shared__ ushort_t As[128 * 32];   // [row][k] row stride 32
    __shared__ ushort_t Bs[128 * 32];   // [n][k]   row stride 32

    const int tid  = threadIdx.x;
    const int w    = tid >> 6;
    const int lane = tid & 63;
    const int quad = lane >> 4;
    const int l16  = lane & 15;
    const int rowBase = blockIdx.y * 128;
    const int nBase   = blockIdx.x * 128;
    const int wr = (w >> 1) * 64;       // wave row offset in tile
    const int wc = (w & 1) * 64;        // wave col offset in tile

    f32x4 acc[4][4];
#pragma unroll
    for (int i = 0; i < 4; i++)
#pragma unroll
        for (int j = 0; j < 4; j++) acc[i][j] = (f32x4){0.f, 0.f, 0.f, 0.f};

    // Staging: 8 chunks of (16 rows x 32 k) per tile; wave w does chunks 2w, 2w+1.
    // Chunk c, lane L: LDS elems c*512 + L*8 ; row = c*16 + (L>>2) ; ksub = (L&3)*8.
    const int c0 = w * 2, c1 = w * 2 + 1;
    const int lrow = lane >> 2;
    const int ksub = (lane & 3) * 8;
    const int ar0 = min(rowBase + c0 * 16 + lrow, M - 1);
    const int ar1 = min(rowBase + c1 * 16 + lrow, M - 1);
    const int br0 = nBase + c0 * 16 + lrow;
    const int br1 = nBase + c1 * 16 + lrow;

    const ushort_t* gA0 = A + (size_t)ar0 * K + ksub;
    const ushort_t* gA1 = A + (size_t)ar1 * K + ksub;
    const ushort_t* gB0 = Bt + (size_t)br0 * K + ksub;
    const ushort_t* gB1 = Bt + (size_t)br1 * K + ksub;
    ushort_t* lA0 = As + c0 * 512 + lane * 8;
    ushort_t* lA1 = As + c1 * 512 + lane * 8;
    ushort_t* lB0 = Bs + c0 * 512 + lane * 8;
    ushort_t* lB1 = Bs + c1 * 512 + lane * 8;

    for (int k0 = 0; k0 < K; k0 += 32) {
        gld_lds16(gA0 + k0, lA0);
        gld_lds16(gA1 + k0, lA1);
        gld_lds16(gB0 + k0, lB0);
        gld_lds16(gB1 + k0, lB1);
        __syncthreads();

        short8 af[4], bfr[4];
#pragma unroll
        for (int mt = 0; mt < 4; mt++)
            af[mt] = *(const short8*)(As + (wr + mt * 16 + l16) * 32 + quad * 8);
#pragma unroll
        for (int nt = 0; nt < 4; nt++)
            bfr[nt] = *(const short8*)(Bs + (wc + nt * 16 + l16) * 32 + quad * 8);
#pragma unroll
        for (int mt = 0; mt < 4; mt++)
#pragma unroll
            for (int nt = 0; nt < 4; nt++)
                acc[mt][nt] = __builtin_amdgcn_mfma_f32_16x16x32_bf16(
                    af[mt], bfr[nt], acc[mt][nt], 0, 0, 0);
        __syncthreads();
    }

    // Epilogue: C/D layout col = lane&15, row = quad*4 + reg
#pragma unroll
    for (int nt = 0; nt < 4; nt++) {
        const int col = nBase + wc + nt * 16 + l16;
        const float bv = bias[col];
#pragma unroll
        for (int mt = 0; mt < 4; mt++) {
#pragma unroll
            for (int r = 0; r < 4; r++) {
                const int row = rowBase + wr + mt * 16 + quad * 4 + r;
                if (row < M) {
                    float v = (acc[mt][nt][r] + bv) * scale;
                    if (relu) v = fmaxf(v, 0.f);
                    C[(size_t)row * N + col] = f2bf(v);
                }
            }
        }
    }
}

// ---------------------------------------------------------------------------
// Weight convert+transpose: W[K][N] f32 -> Wt[N][K] bf16.  64x64 LDS tiles.
// ---------------------------------------------------------------------------
__global__ __launch_bounds__(256) void wt_conv(
    const float* __restrict__ W, ushort_t* __restrict__ Wt, int K, int N)
{
    __shared__ float tile[64][65];
    const int n0 = blockIdx.x * 64, k0 = blockIdx.y * 64;
    const int tr = threadIdx.x >> 6, tc = threadIdx.x & 63;
#pragma unroll
    for (int i = 0; i < 16; i++) {
        int r = i * 4 + tr;
        tile[r][tc] = W[(size_t)(k0 + r) * N + n0 + tc];
    }
    __syncthreads();
#pragma unroll
    for (int i = 0; i < 16; i++) {
        int nr = i * 4 + tr;
        Wt[(size_t)(n0 + nr) * K + k0 + tc] = f2bf(tile[tc][nr]);
    }
}

// ---------------------------------------------------------------------------
// x convert+transpose: x[B][F][49] f32 -> xb[(b*49+s)][F] bf16.
// Block: (b, f-chunk of 256).  Per-thread contiguous 49-float read (L1 reuse),
// coalesced bf16 writes via LDS tile.
// ---------------------------------------------------------------------------
__global__ __launch_bounds__(256) void x_conv(
    const float* __restrict__ x, ushort_t* __restrict__ xb)
{
    __shared__ ushort_t tile[256][50];
    const int b = blockIdx.y, f0 = blockIdx.x * 256, t = threadIdx.x;
    const float* src = x + ((size_t)b * FDIM + f0 + t) * SEQ;
#pragma unroll
    for (int s = 0; s < SEQ; s++) tile[t][s] = f2bf(src[s]);
    __syncthreads();
    for (int s = 0; s < SEQ; s++)
        xb[(size_t)(b * SEQ + s) * FDIM + f0 + t] = tile[t][s];
}

// ---------------------------------------------------------------------------
// LayerNorm over D=768, one block per row, bf16 out.
// out = LN(pre_scale*in + resid) * g + be
// in_bf16: input dtype flag.  rmode: 0 none, 1 full resid, 2 broadcast (row%KQ).
// ---------------------------------------------------------------------------
__device__ __forceinline__ float block_reduce_sum_f(float v, float* red)
{
#pragma unroll
    for (int off = 32; off > 0; off >>= 1) v += __shfl_down(v, off);
    int lane = threadIdx.x & 63, w = threadIdx.x >> 6;
    if (lane == 0) red[w] = v;
    __syncthreads();
    float total = red[0] + red[1] + red[2] + red[3];
    __syncthreads();
    return total;
}

__global__ __launch_bounds__(256) void ln_fused(
    const void* __restrict__ in, int in_bf16,
    const ushort_t* __restrict__ resid, int rmode,
    const float* __restrict__ g, const float* __restrict__ be,
    ushort_t* __restrict__ out, float pre_scale)
{
    __shared__ float red[4];
    const int row = blockIdx.x;
    const int tid = threadIdx.x;

    float v[3];
#pragma unroll
    for (int i = 0; i < 3; i++) {
        int d = tid + i * 256;
        float x;
        if (in_bf16) x = bf2f(((const ushort_t*)in)[(size_t)row * D_MODEL + d]);
        else         x = ((const float*)in)[(size_t)row * D_MODEL + d];
        x *= pre_scale;
        if (rmode == 1)      x += bf2f(resid[(size_t)row * D_MODEL + d]);
        else if (rmode == 2) x += bf2f(resid[(size_t)(row % KQ) * D_MODEL + d]);
        v[i] = x;
    }
    float s = block_reduce_sum_f(v[0] + v[1] + v[2], red);
    float mean = s * (1.f / D_MODEL);
    float d0 = v[0] - mean, d1 = v[1] - mean, d2 = v[2] - mean;
    float sq = block_reduce_sum_f(d0 * d0 + d1 * d1 + d2 * d2, red);
    float rstd = rsqrtf(sq * (1.f / D_MODEL) + 1e-5f);
#pragma unroll
    for (int i = 0; i < 3; i++) {
        int d = tid + i * 256;
        out[(size_t)row * D_MODEL + d] = f2bf((v[i] - mean) * rstd * g[d] + be[d]);
    }
}

// ---------------------------------------------------------------------------
// Cross-attention, one block per (b,h), one wave per query (no block barriers
// in the hot loop).  q pre-scaled by 1/sqrt(96).  K/V staged fp32 in LDS
// (stride 97 -> conflict-free score phase; PV phase is 2-way = free).
// ---------------------------------------------------------------------------
__global__ __launch_bounds__(256) void attn_bf16(
    const ushort_t* __restrict__ q, const ushort_t* __restrict__ k,
    const ushort_t* __restrict__ v, ushort_t* __restrict__ ctx)
{
    __shared__ float Ks[SEQ][HDIM + 1];
    __shared__ float Vs[SEQ][HDIM + 1];
    __shared__ float qsw[4][HDIM];
    __shared__ float psw[4][SEQ];

    const int bh = blockIdx.x;
    const int b = bh >> 3, h = bh & 7;
    const int tid = threadIdx.x, w = tid >> 6, lane = tid & 63;

    for (int idx = tid; idx < SEQ * HDIM; idx += 256) {
        int s = idx / HDIM, dh = idx - s * HDIM;
        size_t ga = (size_t)(b * SEQ + s) * D_MODEL + h * HDIM + dh;
        Ks[s][dh] = bf2f(k[ga]);
        Vs[s][dh] = bf2f(v[ga]);
    }
    __syncthreads();

    for (int kq = w; kq < KQ; kq += 4) {
        // load q row (96 bf16) into this wave's LDS slot
        if (lane < 48) {
            uint_t pair = ((const uint_t*)(q + (size_t)kq * D_MODEL + h * HDIM))[lane];
            qsw[w][2 * lane]     = bf2f((ushort_t)(pair & 0xffff));
            qsw[w][2 * lane + 1] = bf2f((ushort_t)(pair >> 16));
        }
        // scores: lane s in [0,49)
        float sc = -1e30f;
        if (lane < SEQ) {
            float a = 0.f;
#pragma unroll
            for (int d = 0; d < HDIM; d++) a = fmaf(qsw[w][d], Ks[lane][d], a);
            sc = a;
        }
        float mx = sc;
#pragma unroll
        for (int off = 32; off > 0; off >>= 1) mx = fmaxf(mx, __shfl_xor(mx, off));
        float p = (lane < SEQ) ? __expf(sc - mx) : 0.f;
        float sm = p;
#pragma unroll
        for (int off = 32; off > 0; off >>= 1) sm += __shfl_xor(sm, off);
        if (lane < SEQ) psw[w][lane] = p * (1.f / sm);

        // PV: lane covers d=lane and (lane<32) d=lane+64
        float o0 = 0.f, o1 = 0.f;
        for (int s = 0; s < SEQ; s++) {
            float ps = psw[w][s];
            o0 = fmaf(ps, Vs[s][lane], o0);
            if (lane < 32) o1 = fmaf(ps, Vs[s][lane + 64], o1);
        }
        size_t oa = (size_t)(b * KQ + kq) * D_MODEL + h * HDIM;
        ctx[oa + lane] = f2bf(o0);
        if (lane < 32) ctx[oa + lane + 64] = f2bf(o1);
    }
}

// ---------------------------------------------------------------------------
// GroupFC: logits[b, kq*GRP+g] = h[b,kq,:] . dup_pool[kq,:,g] + dup_bias
// ---------------------------------------------------------------------------
__global__ __launch_bounds__(256) void groupfc(
    const ushort_t* __restrict__ h, const float* __restrict__ dp,
    const float* __restrict__ dbias, float* __restrict__ out)
{
    __shared__ float hs[D_MODEL];
    const int bk = blockIdx.x;
    const int b = bk / KQ, kq = bk - b * KQ;
    const int tid = threadIdx.x;

#pragma unroll
    for (int i = 0; i < 3; i++)
        hs[tid + i * 256] = bf2f(h[(size_t)(b * KQ + kq) * D_MODEL + tid + i * 256]);
    __syncthreads();

    const int w = tid >> 6, lane = tid & 63;
    for (int g = w; g < GRP; g += 4) {
        float a = 0.f;
#pragma unroll
        for (int i = 0; i < 12; i++) {
            int d = lane + i * 64;
            a = fmaf(hs[d], dp[(size_t)(kq * D_MODEL + d) * GRP + g], a);
        }
#pragma unroll
        for (int off = 32; off > 0; off >>= 1) a += __shfl_down(a, off);
        if (lane == 0) out[(size_t)b * NCLS + kq * GRP + g] = a + dbias[kq * GRP + g];
    }
}

// ---------------------------------------------------------------------------
extern "C" void kernel_launch(void* const* d_in, const int* in_sizes, int n_in,
                              void* d_out, int out_size, void* d_ws, size_t ws_size,
                              hipStream_t stream)
{
    const float* x   = (const float*)d_in[0];
    const float* We  = (const float*)d_in[1];
    const float* be_ = (const float*)d_in[2];
    const float* qe  = (const float*)d_in[3];
    const float* wq  = (const float*)d_in[4];
    const float* wk  = (const float*)d_in[5];
    const float* wv  = (const float*)d_in[6];
    const float* bq  = (const float*)d_in[7];
    const float* bk  = (const float*)d_in[8];
    const float* bv  = (const float*)d_in[9];
    const float* wo  = (const float*)d_in[10];
    const float* bo  = (const float*)d_in[11];
    const float* w1  = (const float*)d_in[12];
    const float* b1  = (const float*)d_in[13];
    const float* w2  = (const float*)d_in[14];
    const float* b2  = (const float*)d_in[15];
    const float* g1  = (const float*)d_in[16];
    const float* be1 = (const float*)d_in[17];
    const float* g2  = (const float*)d_in[18];
    const float* be2 = (const float*)d_in[19];
    const float* g3  = (const float*)d_in[20];
    const float* be3 = (const float*)d_in[21];
    const float* dp  = (const float*)d_in[22];
    const float* db  = (const float*)d_in[23];
    float* out = (float*)d_out;
    ushort_t* ws = (ushort_t*)d_ws;

    // Workspace (bf16 elems). Region A [0, 27,295,744) time-shared:
    //   phase1: xb | mem | kb | vb     phase2 (>= ffn1): ffh (26,214,400)
    ushort_t* xb  = ws;                      // 6272*2048 = 12,845,056
    ushort_t* mem = xb + 12845056;           // 6272*768  =  4,816,896
    ushort_t* kb  = mem + 4816896;
    ushort_t* vb  = kb + 4816896;
    ushort_t* ffh = ws;                      // 12800*2048 = 26,214,400 (phase2)
    ushort_t* rB  = ws + 27295744;
    ushort_t* Wet = rB;                      // 768*2048 = 1,572,864
    ushort_t* wqt = Wet + 1572864;           // 768*768  =   589,824
    ushort_t* wkt = wqt + 589824;
    ushort_t* wvt = wkt + 589824;
    ushort_t* wot = wvt + 589824;
    ushort_t* w1t = wot + 589824;            // 2048*768 = 1,572,864
    ushort_t* w2t = w1t + 1572864;           // 768*2048 = 1,572,864
    ushort_t* tgt = w2t + 1572864;           // 100*768 = 76,800
    ushort_t* qb  = tgt + 76800;
    ushort_t* ctx = qb + 76800;              // 12800*768 = 9,830,400
    ushort_t* t2  = ctx + 9830400;
    ushort_t* hb  = t2 + 9830400;
    // total = 64,018,432 bf16 = 128.0 MB

    dim3 blk(256);
    const float qscale = 1.0f / sqrtf((float)HDIM);

    // --- conversions (independent of each other) ---
    x_conv<<<dim3(8, NB), blk, 0, stream>>>(x, xb);
    wt_conv<<<dim3(12, 32), blk, 0, stream>>>(We, Wet, FDIM, D_MODEL);   // 2048x768
    wt_conv<<<dim3(12, 12), blk, 0, stream>>>(wq, wqt, D_MODEL, D_MODEL);
    wt_conv<<<dim3(12, 12), blk, 0, stream>>>(wk, wkt, D_MODEL, D_MODEL);
    wt_conv<<<dim3(12, 12), blk, 0, stream>>>(wv, wvt, D_MODEL, D_MODEL);
    wt_conv<<<dim3(12, 12), blk, 0, stream>>>(wo, wot, D_MODEL, D_MODEL);
    wt_conv<<<dim3(32, 12), blk, 0, stream>>>(w1, w1t, D_MODEL, FFD);    // 768x2048
    wt_conv<<<dim3(12, 32), blk, 0, stream>>>(w2, w2t, FFD, D_MODEL);    // 2048x768

    // --- pipeline ---
    // 1. mem = relu(xb @ We + b_embed)          [6272 x 768, K=2048]
    gemm_bf16<<<dim3(6, 49), blk, 0, stream>>>(xb, Wet, be_, mem, 6272, 768, 2048, 1, 1.f);
    // 2. tgt = LN(2*qe)                         [100 x 768]
    ln_fused<<<dim3(KQ), blk, 0, stream>>>(qe, 0, nullptr, 0, g1, be1, tgt, 2.0f);
    // 3. qb = (tgt@wq + bq)/sqrt(96)            [100 x 768, K=768]
    gemm_bf16<<<dim3(6, 1), blk, 0, stream>>>(tgt, wqt, bq, qb, KQ, 768, 768, 0, qscale);
    // 4/5. k, v                                 [6272 x 768, K=768]
    gemm_bf16<<<dim3(6, 49), blk, 0, stream>>>(mem, wkt, bk, kb, 6272, 768, 768, 0, 1.f);
    gemm_bf16<<<dim3(6, 49), blk, 0, stream>>>(mem, wvt, bv, vb, 6272, 768, 768, 0, 1.f);
    // 6. attention -> ctx                       [B*H blocks]
    attn_bf16<<<dim3(NB * HEADS), blk, 0, stream>>>(qb, kb, vb, ctx);
    // 7. t2 = ctx@wo + bo                       [12800 x 768, K=768]
    gemm_bf16<<<dim3(6, 100), blk, 0, stream>>>(ctx, wot, bo, t2, 12800, 768, 768, 0, 1.f);
    // 8. t2 = LN(t2 + bcast tgt)                in place
    ln_fused<<<dim3(12800), blk, 0, stream>>>(t2, 1, tgt, 2, g2, be2, t2, 1.0f);
    // 9. ffh = relu(t2@w1 + b1)                 [12800 x 2048, K=768]
    gemm_bf16<<<dim3(16, 100), blk, 0, stream>>>(t2, w1t, b1, ffh, 12800, 2048, 768, 1, 1.f);
    // 10. hb = ffh@w2 + b2                      [12800 x 768, K=2048]
    gemm_bf16<<<dim3(6, 100), blk, 0, stream>>>(ffh, w2t, b2, hb, 12800, 768, 2048, 0, 1.f);
    // 11. hb = LN(hb + t2)                      in place
    ln_fused<<<dim3(12800), blk, 0, stream>>>(hb, 1, t2, 1, g3, be3, hb, 1.0f);
    // 12. GroupFC -> out (fp32 logits)
    groupfc<<<dim3(12800), blk, 0, stream>>>(hb, dp, db, out);
}

// Round 3
// 695.507 us; speedup vs baseline: 4.1455x; 1.1680x over previous
//
#include <hip/hip_runtime.h>
#include <math.h>

#define D_MODEL 768
#define HEADS   8
#define HDIM    96
#define SEQ     49
#define KQ      100
#define NB      128
#define FDIM    2048
#define FFD     2048
#define GRP     10
#define NCLS    1000

typedef unsigned short ushort_t;
typedef unsigned int uint_t;
typedef __attribute__((ext_vector_type(8))) short short8;
typedef __attribute__((ext_vector_type(4))) float f32x4;

// ---------------------------------------------------------------------------
// bf16 helpers (RNE rounding)
// ---------------------------------------------------------------------------
__device__ __forceinline__ float bf2f(ushort_t u) {
    uint_t x = ((uint_t)u) << 16;
    return __uint_as_float(x);
}
__device__ __forceinline__ ushort_t f2bf(float f) {
    uint_t x = __float_as_uint(f);
    x += 0x7fffu + ((x >> 16) & 1u);
    return (ushort_t)(x >> 16);
}

// async global->LDS, 16 bytes per lane (lds dest = wave-uniform base + lane*16)
__device__ __forceinline__ void gld_lds16(const void* g, void* l) {
    __builtin_amdgcn_global_load_lds(
        (const __attribute__((address_space(1))) unsigned int*)g,
        (__attribute__((address_space(3))) unsigned int*)l, 16, 0, 0);
}

// ---------------------------------------------------------------------------
// bf16 MFMA GEMM (m97 structure): C[M,N] = act((A@B + bias)*scale), bf16 out.
// A: [M][K] bf16 row-major.  Bt: [N][K] bf16 row-major (B transposed).
// 128x128 tile, BK=32, 256 thr = 4 waves, each wave 64x64 (4x4 of 16x16x32).
// ---------------------------------------------------------------------------
__global__ __launch_bounds__(256) void gemm_bf16(
    const ushort_t* __restrict__ A, const ushort_t* __restrict__ Bt,
    const float* __restrict__ bias, ushort_t* __restrict__ C,
    int M, int N, int K, int relu, float scale)
{
    __shared__ ushort_t As[128 * 32];   // [row][k] row stride 32
    __shared__ ushort_t Bs[128 * 32];   // [n][k]   row stride 32

    const int tid  = threadIdx.x;
    const int w    = tid >> 6;
    const int lane = tid & 63;
    const int quad = lane >> 4;
    const int l16  = lane & 15;
    const int rowBase = blockIdx.y * 128;
    const int nBase   = blockIdx.x * 128;
    const int wr = (w >> 1) * 64;
    const int wc = (w & 1) * 64;

    f32x4 acc[4][4];
#pragma unroll
    for (int i = 0; i < 4; i++)
#pragma unroll
        for (int j = 0; j < 4; j++) acc[i][j] = (f32x4){0.f, 0.f, 0.f, 0.f};

    const int c0 = w * 2, c1 = w * 2 + 1;
    const int lrow = lane >> 2;
    const int ksub = (lane & 3) * 8;
    const int ar0 = min(rowBase + c0 * 16 + lrow, M - 1);
    const int ar1 = min(rowBase + c1 * 16 + lrow, M - 1);
    const int br0 = nBase + c0 * 16 + lrow;
    const int br1 = nBase + c1 * 16 + lrow;

    const ushort_t* gA0 = A + (size_t)ar0 * K + ksub;
    const ushort_t* gA1 = A + (size_t)ar1 * K + ksub;
    const ushort_t* gB0 = Bt + (size_t)br0 * K + ksub;
    const ushort_t* gB1 = Bt + (size_t)br1 * K + ksub;
    ushort_t* lA0 = As + c0 * 512 + lane * 8;
    ushort_t* lA1 = As + c1 * 512 + lane * 8;
    ushort_t* lB0 = Bs + c0 * 512 + lane * 8;
    ushort_t* lB1 = Bs + c1 * 512 + lane * 8;

    for (int k0 = 0; k0 < K; k0 += 32) {
        gld_lds16(gA0 + k0, lA0);
        gld_lds16(gA1 + k0, lA1);
        gld_lds16(gB0 + k0, lB0);
        gld_lds16(gB1 + k0, lB1);
        __syncthreads();

        short8 af[4], bfr[4];
#pragma unroll
        for (int mt = 0; mt < 4; mt++)
            af[mt] = *(const short8*)(As + (wr + mt * 16 + l16) * 32 + quad * 8);
#pragma unroll
        for (int nt = 0; nt < 4; nt++)
            bfr[nt] = *(const short8*)(Bs + (wc + nt * 16 + l16) * 32 + quad * 8);
#pragma unroll
        for (int mt = 0; mt < 4; mt++)
#pragma unroll
            for (int nt = 0; nt < 4; nt++)
                acc[mt][nt] = __builtin_amdgcn_mfma_f32_16x16x32_bf16(
                    af[mt], bfr[nt], acc[mt][nt], 0, 0, 0);
        __syncthreads();
    }

#pragma unroll
    for (int nt = 0; nt < 4; nt++) {
        const int col = nBase + wc + nt * 16 + l16;
        const float bv = bias[col];
#pragma unroll
        for (int mt = 0; mt < 4; mt++) {
#pragma unroll
            for (int r = 0; r < 4; r++) {
                const int row = rowBase + wr + mt * 16 + quad * 4 + r;
                if (row < M) {
                    float v = (acc[mt][nt][r] + bv) * scale;
                    if (relu) v = fmaxf(v, 0.f);
                    C[(size_t)row * N + col] = f2bf(v);
                }
            }
        }
    }
}

// ---------------------------------------------------------------------------
// Weight convert+transpose: W[K][N] f32 -> Wt[N][K] bf16.
// ---------------------------------------------------------------------------
__global__ __launch_bounds__(256) void wt_conv(
    const float* __restrict__ W, ushort_t* __restrict__ Wt, int K, int N)
{
    __shared__ float tile[64][65];
    const int n0 = blockIdx.x * 64, k0 = blockIdx.y * 64;
    const int tr = threadIdx.x >> 6, tc = threadIdx.x & 63;
#pragma unroll
    for (int i = 0; i < 16; i++) {
        int r = i * 4 + tr;
        tile[r][tc] = W[(size_t)(k0 + r) * N + n0 + tc];
    }
    __syncthreads();
#pragma unroll
    for (int i = 0; i < 16; i++) {
        int nr = i * 4 + tr;
        Wt[(size_t)(n0 + nr) * K + k0 + tc] = f2bf(tile[tc][nr]);
    }
}

// ---------------------------------------------------------------------------
// x convert+transpose: x[B][F][49] f32 -> xb[(b*49+s)][F] bf16.
// ---------------------------------------------------------------------------
__global__ __launch_bounds__(256) void x_conv(
    const float* __restrict__ x, ushort_t* __restrict__ xb)
{
    __shared__ ushort_t tile[256][50];
    const int b = blockIdx.y, f0 = blockIdx.x * 256, t = threadIdx.x;
    const float* src = x + ((size_t)b * FDIM + f0 + t) * SEQ;
#pragma unroll
    for (int s = 0; s < SEQ; s++) tile[t][s] = f2bf(src[s]);
    __syncthreads();
    for (int s = 0; s < SEQ; s++)
        xb[(size_t)(b * SEQ + s) * FDIM + f0 + t] = tile[t][s];
}

// ---------------------------------------------------------------------------
// LayerNorm over D=768, one block per row, bf16 out.
// ---------------------------------------------------------------------------
__device__ __forceinline__ float block_reduce_sum_f(float v, float* red)
{
#pragma unroll
    for (int off = 32; off > 0; off >>= 1) v += __shfl_down(v, off);
    int lane = threadIdx.x & 63, w = threadIdx.x >> 6;
    if (lane == 0) red[w] = v;
    __syncthreads();
    float total = red[0] + red[1] + red[2] + red[3];
    __syncthreads();
    return total;
}

__global__ __launch_bounds__(256) void ln_fused(
    const void* __restrict__ in, int in_bf16,
    const ushort_t* __restrict__ resid, int rmode,
    const float* __restrict__ g, const float* __restrict__ be,
    ushort_t* __restrict__ out, float pre_scale)
{
    __shared__ float red[4];
    const int row = blockIdx.x;
    const int tid = threadIdx.x;

    float v[3];
#pragma unroll
    for (int i = 0; i < 3; i++) {
        int d = tid + i * 256;
        float x;
        if (in_bf16) x = bf2f(((const ushort_t*)in)[(size_t)row * D_MODEL + d]);
        else         x = ((const float*)in)[(size_t)row * D_MODEL + d];
        x *= pre_scale;
        if (rmode == 1)      x += bf2f(resid[(size_t)row * D_MODEL + d]);
        else if (rmode == 2) x += bf2f(resid[(size_t)(row % KQ) * D_MODEL + d]);
        v[i] = x;
    }
    float s = block_reduce_sum_f(v[0] + v[1] + v[2], red);
    float mean = s * (1.f / D_MODEL);
    float d0 = v[0] - mean, d1 = v[1] - mean, d2 = v[2] - mean;
    float sq = block_reduce_sum_f(d0 * d0 + d1 * d1 + d2 * d2, red);
    float rstd = rsqrtf(sq * (1.f / D_MODEL) + 1e-5f);
#pragma unroll
    for (int i = 0; i < 3; i++) {
        int d = tid + i * 256;
        out[(size_t)row * D_MODEL + d] = f2bf((v[i] - mean) * rstd * g[d] + be[d]);
    }
}

// ---------------------------------------------------------------------------
// MFMA cross-attention, one block per (b,h), 4 waves; wave w owns query rows
// 32w..32w+31 (M padded to 128, clamp reads, guard stores).
//   S = Q K^T : A/B frags (K-major, 16B/lane) gathered DIRECTLY from global
//               (q,k are L2-resident; no LDS staging). N=64 pad over S=49,
//               fake cols masked in softmax.
//   softmax   : in C-layout registers; row lives in the 16 l16-lanes of one
//               quad -> butterfly __shfl_xor {1,2,4,8}. P*inv_sum -> LDS
//               Pt[128][72] bf16 (stride 72 => 2-way bank alias on b128 =
//               free); padded cols written as exact 0.
//   O = P V   : Vt[96][72] staged once (cols>=49 zeroed), 2 k-iters of 32.
// ---------------------------------------------------------------------------
__global__ __launch_bounds__(256) void attn_mfma(
    const ushort_t* __restrict__ q, const ushort_t* __restrict__ k,
    const ushort_t* __restrict__ v, ushort_t* __restrict__ ctx)
{
    __shared__ ushort_t Pt[128][72];
    __shared__ ushort_t Vt[96][72];

    const int bh = blockIdx.x;
    const int b = bh >> 3, h = bh & 7;
    const int tid = threadIdx.x;
    const int w = tid >> 6, lane = tid & 63;
    const int quad = lane >> 4, l16 = lane & 15;
    const int mrow0 = 32 * w;

    // stage V^T (zero-fill padded key cols)
    for (int idx = tid; idx < 96 * 64; idx += 256) {
        int d = idx >> 6, s = idx & 63;
        ushort_t val = 0;
        if (s < SEQ) val = v[(size_t)(b * SEQ + s) * D_MODEL + h * HDIM + d];
        Vt[d][s] = val;
    }

    // ---- S = Q K^T (rows mrow0..mrow0+31, cols 0..63) ----
    f32x4 accS[2][4];
#pragma unroll
    for (int i = 0; i < 2; i++)
#pragma unroll
        for (int j = 0; j < 4; j++) accS[i][j] = (f32x4){0.f, 0.f, 0.f, 0.f};

#pragma unroll
    for (int k0 = 0; k0 < HDIM; k0 += 32) {
        short8 af[2], bfr[4];
#pragma unroll
        for (int mt = 0; mt < 2; mt++) {
            int kq = min(mrow0 + mt * 16 + l16, KQ - 1);
            af[mt] = *(const short8*)(q + (size_t)kq * D_MODEL + h * HDIM + k0 + quad * 8);
        }
#pragma unroll
        for (int nt = 0; nt < 4; nt++) {
            int s = min(nt * 16 + l16, SEQ - 1);
            bfr[nt] = *(const short8*)(k + (size_t)(b * SEQ + s) * D_MODEL + h * HDIM + k0 + quad * 8);
        }
#pragma unroll
        for (int mt = 0; mt < 2; mt++)
#pragma unroll
            for (int nt = 0; nt < 4; nt++)
                accS[mt][nt] = __builtin_amdgcn_mfma_f32_16x16x32_bf16(
                    af[mt], bfr[nt], accS[mt][nt], 0, 0, 0);
    }

    // ---- softmax in C-layout registers; write P (bf16, normalized) ----
#pragma unroll
    for (int mt = 0; mt < 2; mt++) {
#pragma unroll
        for (int r = 0; r < 4; r++) {
            float vals[4];
            float vmax = -1e30f;
#pragma unroll
            for (int nt = 0; nt < 4; nt++) {
                vals[nt] = accS[mt][nt][r];
                if (nt * 16 + l16 < SEQ) vmax = fmaxf(vmax, vals[nt]);
            }
#pragma unroll
            for (int off = 1; off < 16; off <<= 1)
                vmax = fmaxf(vmax, __shfl_xor(vmax, off));
            float p[4], psum = 0.f;
#pragma unroll
            for (int nt = 0; nt < 4; nt++) {
                float e = (nt * 16 + l16 < SEQ) ? __expf(vals[nt] - vmax) : 0.f;
                p[nt] = e;
                psum += e;
            }
#pragma unroll
            for (int off = 1; off < 16; off <<= 1)
                psum += __shfl_xor(psum, off);
            const float inv = 1.f / psum;
            const int row = mrow0 + mt * 16 + quad * 4 + r;
#pragma unroll
            for (int nt = 0; nt < 4; nt++)
                Pt[row][nt * 16 + l16] = f2bf(p[nt] * inv);
        }
    }
    __syncthreads();   // Vt + P visible

    // ---- O = P * V  (M=128, N=96, K=64) ----
    f32x4 accO[2][6];
#pragma unroll
    for (int i = 0; i < 2; i++)
#pragma unroll
        for (int j = 0; j < 6; j++) accO[i][j] = (f32x4){0.f, 0.f, 0.f, 0.f};

#pragma unroll
    for (int k0 = 0; k0 < 64; k0 += 32) {
        short8 af[2], bfr[6];
#pragma unroll
        for (int mt = 0; mt < 2; mt++)
            af[mt] = *(const short8*)(&Pt[mrow0 + mt * 16 + l16][k0 + quad * 8]);
#pragma unroll
        for (int nt = 0; nt < 6; nt++)
            bfr[nt] = *(const short8*)(&Vt[nt * 16 + l16][k0 + quad * 8]);
#pragma unroll
        for (int mt = 0; mt < 2; mt++)
#pragma unroll
            for (int nt = 0; nt < 6; nt++)
                accO[mt][nt] = __builtin_amdgcn_mfma_f32_16x16x32_bf16(
                    af[mt], bfr[nt], accO[mt][nt], 0, 0, 0);
    }

    // epilogue: d = nt*16+l16, kq = mrow0 + mt*16 + quad*4 + r
#pragma unroll
    for (int mt = 0; mt < 2; mt++) {
#pragma unroll
        for (int r = 0; r < 4; r++) {
            const int kq = mrow0 + mt * 16 + quad * 4 + r;
            if (kq < KQ) {
                size_t oa = (size_t)(b * KQ + kq) * D_MODEL + h * HDIM;
#pragma unroll
                for (int nt = 0; nt < 6; nt++)
                    ctx[oa + nt * 16 + l16] = f2bf(accO[mt][nt][r]);
            }
        }
    }
}

// ---------------------------------------------------------------------------
// GroupFC: logits[b, kq*GRP+g] = h[b,kq,:] . dup_pool[kq,:,g] + dup_bias
// ---------------------------------------------------------------------------
__global__ __launch_bounds__(256) void groupfc(
    const ushort_t* __restrict__ h, const float* __restrict__ dp,
    const float* __restrict__ dbias, float* __restrict__ out)
{
    __shared__ float hs[D_MODEL];
    const int bk = blockIdx.x;
    const int b = bk / KQ, kq = bk - b * KQ;
    const int tid = threadIdx.x;

#pragma unroll
    for (int i = 0; i < 3; i++)
        hs[tid + i * 256] = bf2f(h[(size_t)(b * KQ + kq) * D_MODEL + tid + i * 256]);
    __syncthreads();

    const int w = tid >> 6, lane = tid & 63;
    for (int g = w; g < GRP; g += 4) {
        float a = 0.f;
#pragma unroll
        for (int i = 0; i < 12; i++) {
            int d = lane + i * 64;
            a = fmaf(hs[d], dp[(size_t)(kq * D_MODEL + d) * GRP + g], a);
        }
#pragma unroll
        for (int off = 32; off > 0; off >>= 1) a += __shfl_down(a, off);
        if (lane == 0) out[(size_t)b * NCLS + kq * GRP + g] = a + dbias[kq * GRP + g];
    }
}

// ---------------------------------------------------------------------------
extern "C" void kernel_launch(void* const* d_in, const int* in_sizes, int n_in,
                              void* d_out, int out_size, void* d_ws, size_t ws_size,
                              hipStream_t stream)
{
    const float* x   = (const float*)d_in[0];
    const float* We  = (const float*)d_in[1];
    const float* be_ = (const float*)d_in[2];
    const float* qe  = (const float*)d_in[3];
    const float* wq  = (const float*)d_in[4];
    const float* wk  = (const float*)d_in[5];
    const float* wv  = (const float*)d_in[6];
    const float* bq  = (const float*)d_in[7];
    const float* bk  = (const float*)d_in[8];
    const float* bv  = (const float*)d_in[9];
    const float* wo  = (const float*)d_in[10];
    const float* bo  = (const float*)d_in[11];
    const float* w1  = (const float*)d_in[12];
    const float* b1  = (const float*)d_in[13];
    const float* w2  = (const float*)d_in[14];
    const float* b2  = (const float*)d_in[15];
    const float* g1  = (const float*)d_in[16];
    const float* be1 = (const float*)d_in[17];
    const float* g2  = (const float*)d_in[18];
    const float* be2 = (const float*)d_in[19];
    const float* g3  = (const float*)d_in[20];
    const float* be3 = (const float*)d_in[21];
    const float* dp  = (const float*)d_in[22];
    const float* db  = (const float*)d_in[23];
    float* out = (float*)d_out;
    ushort_t* ws = (ushort_t*)d_ws;

    // Workspace (bf16 elems). Region A [0, 27,295,744) time-shared:
    //   phase1: xb | mem | kb | vb     phase2 (>= ffn1): ffh (26,214,400)
    ushort_t* xb  = ws;                      // 6272*2048 = 12,845,056
    ushort_t* mem = xb + 12845056;           // 6272*768  =  4,816,896
    ushort_t* kb  = mem + 4816896;
    ushort_t* vb  = kb + 4816896;
    ushort_t* ffh = ws;                      // 12800*2048 = 26,214,400 (phase2)
    ushort_t* rB  = ws + 27295744;
    ushort_t* Wet = rB;                      // 768*2048 = 1,572,864
    ushort_t* wqt = Wet + 1572864;           // 768*768  =   589,824
    ushort_t* wkt = wqt + 589824;
    ushort_t* wvt = wkt + 589824;
    ushort_t* wot = wvt + 589824;
    ushort_t* w1t = wot + 589824;            // 2048*768 = 1,572,864
    ushort_t* w2t = w1t + 1572864;           // 768*2048 = 1,572,864
    ushort_t* tgt = w2t + 1572864;           // 100*768 = 76,800
    ushort_t* qb  = tgt + 76800;
    ushort_t* ctx = qb + 76800;              // 12800*768 = 9,830,400
    ushort_t* t2  = ctx + 9830400;
    ushort_t* hb  = t2 + 9830400;

    dim3 blk(256);
    const float qscale = 1.0f / sqrtf((float)HDIM);

    // --- conversions ---
    x_conv<<<dim3(8, NB), blk, 0, stream>>>(x, xb);
    wt_conv<<<dim3(12, 32), blk, 0, stream>>>(We, Wet, FDIM, D_MODEL);
    wt_conv<<<dim3(12, 12), blk, 0, stream>>>(wq, wqt, D_MODEL, D_MODEL);
    wt_conv<<<dim3(12, 12), blk, 0, stream>>>(wk, wkt, D_MODEL, D_MODEL);
    wt_conv<<<dim3(12, 12), blk, 0, stream>>>(wv, wvt, D_MODEL, D_MODEL);
    wt_conv<<<dim3(12, 12), blk, 0, stream>>>(wo, wot, D_MODEL, D_MODEL);
    wt_conv<<<dim3(32, 12), blk, 0, stream>>>(w1, w1t, D_MODEL, FFD);
    wt_conv<<<dim3(12, 32), blk, 0, stream>>>(w2, w2t, FFD, D_MODEL);

    // --- pipeline ---
    gemm_bf16<<<dim3(6, 49), blk, 0, stream>>>(xb, Wet, be_, mem, 6272, 768, 2048, 1, 1.f);
    ln_fused<<<dim3(KQ), blk, 0, stream>>>(qe, 0, nullptr, 0, g1, be1, tgt, 2.0f);
    gemm_bf16<<<dim3(6, 1), blk, 0, stream>>>(tgt, wqt, bq, qb, KQ, 768, 768, 0, qscale);
    gemm_bf16<<<dim3(6, 49), blk, 0, stream>>>(mem, wkt, bk, kb, 6272, 768, 768, 0, 1.f);
    gemm_bf16<<<dim3(6, 49), blk, 0, stream>>>(mem, wvt, bv, vb, 6272, 768, 768, 0, 1.f);
    attn_mfma<<<dim3(NB * HEADS), blk, 0, stream>>>(qb, kb, vb, ctx);
    gemm_bf16<<<dim3(6, 100), blk, 0, stream>>>(ctx, wot, bo, t2, 12800, 768, 768, 0, 1.f);
    ln_fused<<<dim3(12800), blk, 0, stream>>>(t2, 1, tgt, 2, g2, be2, t2, 1.0f);
    gemm_bf16<<<dim3(16, 100), blk, 0, stream>>>(t2, w1t, b1, ffh, 12800, 2048, 768, 1, 1.f);
    gemm_bf16<<<dim3(6, 100), blk, 0, stream>>>(ffh, w2t, b2, hb, 12800, 768, 2048, 0, 1.f);
    ln_fused<<<dim3(12800), blk, 0, stream>>>(hb, 1, t2, 1, g3, be3, hb, 1.0f);
    groupfc<<<dim3(12800), blk, 0, stream>>>(hb, dp, db, out);
}

// Round 4
// 569.617 us; speedup vs baseline: 5.0616x; 1.2210x over previous
//
#include <hip/hip_runtime.h>
#include <math.h>

#define D_MODEL 768
#define HEADS   8
#define HDIM    96
#define SEQ     49
#define KQ      100
#define NB      128
#define FDIM    2048
#define FFD     2048
#define GRP     10
#define NCLS    1000

typedef unsigned short ushort_t;
typedef unsigned int uint_t;
typedef __attribute__((ext_vector_type(8))) short short8;
typedef __attribute__((ext_vector_type(4))) float f32x4;

// ---------------------------------------------------------------------------
// bf16 helpers (RNE rounding)
// ---------------------------------------------------------------------------
__device__ __forceinline__ float bf2f(ushort_t u) {
    uint_t x = ((uint_t)u) << 16;
    return __uint_as_float(x);
}
__device__ __forceinline__ ushort_t f2bf(float f) {
    uint_t x = __float_as_uint(f);
    x += 0x7fffu + ((x >> 16) & 1u);
    return (ushort_t)(x >> 16);
}

// async global->LDS, 16 bytes per lane (lds dest = wave-uniform base + lane*16)
__device__ __forceinline__ void gld_lds16(const void* g, void* l) {
    __builtin_amdgcn_global_load_lds(
        (const __attribute__((address_space(1))) unsigned int*)g,
        (__attribute__((address_space(3))) unsigned int*)l, 16, 0, 0);
}

// ---------------------------------------------------------------------------
// bf16 MFMA GEMM, swizzled LDS (bank-conflict-free frag reads).
// A: [M][K] bf16 row-major.  Bt: [N][K] bf16 row-major.
// Block tile: (MT*32) x 128, BK=32, 256 thr = 4 waves (2x2), wave = (MT*16)x64.
// Split-N output: cols < nsplit -> C (bias), cols >= nsplit -> C2 (bias2);
// both sides use row stride = their own width (nsplit / N-nsplit). For an
// unsplit GEMM pass nsplit == N.  nsplit must be a multiple of 128.
//
// Swizzle: staging lane L (lrow=L>>2, q0=L&3) fetches global k-chunk
// (q0 ^ ((lrow>>1)&3)) into LDS slot q0; frag reader uses slot
// quad ^ ((l16>>1)&3) -> content is global chunk `quad`. b128 reads then
// spread over 8 bank-quads (2-way = free) instead of 2 (8-way).
// ---------------------------------------------------------------------------
template <int MT>
__global__ __launch_bounds__(256, (MT == 2 ? 4 : 3)) void gemm_bf16(
    const ushort_t* __restrict__ A, const ushort_t* __restrict__ Bt,
    const float* __restrict__ bias, const float* __restrict__ bias2,
    ushort_t* __restrict__ C, ushort_t* __restrict__ C2,
    int M, int N, int K, int nsplit, int relu, float scale)
{
    constexpr int BM  = MT * 32;        // block rows
    constexpr int ACH = MT * 2;         // A chunks (16 rows x 32 k each)
    constexpr int NCH = (ACH + 8) / 4;  // staging chunks per wave

    __shared__ ushort_t As[BM * 32];
    __shared__ ushort_t Bs[128 * 32];

    const int tid  = threadIdx.x;
    const int w    = tid >> 6;
    const int lane = tid & 63;
    const int quad = lane >> 4;
    const int l16  = lane & 15;
    const int rowBase = blockIdx.y * BM;
    const int nBase   = blockIdx.x * 128;
    const int wr = (w >> 1) * (MT * 16);
    const int wc = (w & 1) * 64;

    // per-block output side (nsplit multiple of 128 -> uniform per block)
    const float* biasb;
    ushort_t* Cb;
    int coff, ldcb;
    if (nBase < nsplit) { biasb = bias;  Cb = C;  coff = 0;      ldcb = nsplit; }
    else                { biasb = bias2; Cb = C2; coff = nsplit; ldcb = N - nsplit; }

    f32x4 acc[MT][4];
#pragma unroll
    for (int i = 0; i < MT; i++)
#pragma unroll
        for (int j = 0; j < 4; j++) acc[i][j] = (f32x4){0.f, 0.f, 0.f, 0.f};

    const int lrow = lane >> 2;
    const int ksub = (((lane & 3) ^ ((lrow >> 1) & 3))) * 8;   // swizzled source chunk

    const ushort_t* gp[NCH];
    ushort_t* lp[NCH];
#pragma unroll
    for (int i = 0; i < NCH; i++) {
        int c = w + 4 * i;
        if (c < ACH) {
            int r = min(rowBase + c * 16 + lrow, M - 1);
            gp[i] = A + (size_t)r * K + ksub;
            lp[i] = As + c * 512 + lane * 8;
        } else {
            int cb = c - ACH;
            int r = nBase + cb * 16 + lrow;
            gp[i] = Bt + (size_t)r * K + ksub;
            lp[i] = Bs + cb * 512 + lane * 8;
        }
    }

    const int ksw = (quad ^ ((l16 >> 1) & 3)) * 8;             // swizzled frag slot

    for (int k0 = 0; k0 < K; k0 += 32) {
#pragma unroll
        for (int i = 0; i < NCH; i++) gld_lds16(gp[i] + k0, lp[i]);
        __syncthreads();

        short8 af[MT], bfr[4];
#pragma unroll
        for (int mt = 0; mt < MT; mt++)
            af[mt] = *(const short8*)(As + (wr + mt * 16 + l16) * 32 + ksw);
#pragma unroll
        for (int nt = 0; nt < 4; nt++)
            bfr[nt] = *(const short8*)(Bs + (wc + nt * 16 + l16) * 32 + ksw);
#pragma unroll
        for (int mt = 0; mt < MT; mt++)
#pragma unroll
            for (int nt = 0; nt < 4; nt++)
                acc[mt][nt] = __builtin_amdgcn_mfma_f32_16x16x32_bf16(
                    af[mt], bfr[nt], acc[mt][nt], 0, 0, 0);
        __syncthreads();
    }

    // Epilogue: C/D layout col = lane&15, row = quad*4 + reg
#pragma unroll
    for (int nt = 0; nt < 4; nt++) {
        const int colg = nBase + wc + nt * 16 + l16;
        const int col  = colg - coff;
        const float bv = biasb[col];
#pragma unroll
        for (int mt = 0; mt < MT; mt++) {
#pragma unroll
            for (int r = 0; r < 4; r++) {
                const int row = rowBase + wr + mt * 16 + quad * 4 + r;
                if (row < M) {
                    float v = (acc[mt][nt][r] + bv) * scale;
                    if (relu) v = fmaxf(v, 0.f);
                    Cb[(size_t)row * ldcb + col] = f2bf(v);
                }
            }
        }
    }
}

// ---------------------------------------------------------------------------
// All 7 weight matrices converted+transposed in ONE dispatch.
// W[K][N] f32 -> Wt[N][K] bf16, 64x64 tiles.  1728 tiles total.
// ---------------------------------------------------------------------------
__global__ __launch_bounds__(256) void wt_conv_all(
    const float* __restrict__ We, const float* __restrict__ wq,
    const float* __restrict__ wk, const float* __restrict__ wv,
    const float* __restrict__ wo, const float* __restrict__ w1,
    const float* __restrict__ w2,
    ushort_t* __restrict__ Wet, ushort_t* __restrict__ wqt,
    ushort_t* __restrict__ wkt, ushort_t* __restrict__ wvt,
    ushort_t* __restrict__ wot, ushort_t* __restrict__ w1t,
    ushort_t* __restrict__ w2t)
{
    __shared__ float tile[64][65];
    int t = blockIdx.x;
    const float* src; ushort_t* dst; int K, N, tx;
    if (t < 384)       {           src = We; dst = Wet; K = 2048; N = 768;  tx = 12; }
    else if (t < 528)  { t -= 384; src = wq; dst = wqt; K = 768;  N = 768;  tx = 12; }
    else if (t < 672)  { t -= 528; src = wk; dst = wkt; K = 768;  N = 768;  tx = 12; }
    else if (t < 816)  { t -= 672; src = wv; dst = wvt; K = 768;  N = 768;  tx = 12; }
    else if (t < 960)  { t -= 816; src = wo; dst = wot; K = 768;  N = 768;  tx = 12; }
    else if (t < 1344) { t -= 960; src = w1; dst = w1t; K = 768;  N = 2048; tx = 32; }
    else               { t -= 1344; src = w2; dst = w2t; K = 2048; N = 768; tx = 12; }
    const int n0 = (t % tx) * 64, k0 = (t / tx) * 64;
    const int tr = threadIdx.x >> 6, tc = threadIdx.x & 63;
#pragma unroll
    for (int i = 0; i < 16; i++) {
        int r = i * 4 + tr;
        tile[r][tc] = src[(size_t)(k0 + r) * N + n0 + tc];
    }
    __syncthreads();
#pragma unroll
    for (int i = 0; i < 16; i++) {
        int nr = i * 4 + tr;
        dst[(size_t)(n0 + nr) * K + k0 + tc] = f2bf(tile[tc][nr]);
    }
}

// ---------------------------------------------------------------------------
// x convert+transpose: x[B][F][49] f32 -> xb[(b*49+s)][F] bf16.
// ---------------------------------------------------------------------------
__global__ __launch_bounds__(256) void x_conv(
    const float* __restrict__ x, ushort_t* __restrict__ xb)
{
    __shared__ ushort_t tile[256][50];
    const int b = blockIdx.y, f0 = blockIdx.x * 256, t = threadIdx.x;
    const float* src = x + ((size_t)b * FDIM + f0 + t) * SEQ;
#pragma unroll
    for (int s = 0; s < SEQ; s++) tile[t][s] = f2bf(src[s]);
    __syncthreads();
    for (int s = 0; s < SEQ; s++)
        xb[(size_t)(b * SEQ + s) * FDIM + f0 + t] = tile[t][s];
}

// ---------------------------------------------------------------------------
// LayerNorm over D=768, one block per row, bf16 out.
// ---------------------------------------------------------------------------
__device__ __forceinline__ float block_reduce_sum_f(float v, float* red)
{
#pragma unroll
    for (int off = 32; off > 0; off >>= 1) v += __shfl_down(v, off);
    int lane = threadIdx.x & 63, w = threadIdx.x >> 6;
    if (lane == 0) red[w] = v;
    __syncthreads();
    float total = red[0] + red[1] + red[2] + red[3];
    __syncthreads();
    return total;
}

__global__ __launch_bounds__(256) void ln_fused(
    const void* __restrict__ in, int in_bf16,
    const ushort_t* __restrict__ resid, int rmode,
    const float* __restrict__ g, const float* __restrict__ be,
    ushort_t* __restrict__ out, float pre_scale)
{
    __shared__ float red[4];
    const int row = blockIdx.x;
    const int tid = threadIdx.x;

    float v[3];
#pragma unroll
    for (int i = 0; i < 3; i++) {
        int d = tid + i * 256;
        float x;
        if (in_bf16) x = bf2f(((const ushort_t*)in)[(size_t)row * D_MODEL + d]);
        else         x = ((const float*)in)[(size_t)row * D_MODEL + d];
        x *= pre_scale;
        if (rmode == 1)      x += bf2f(resid[(size_t)row * D_MODEL + d]);
        else if (rmode == 2) x += bf2f(resid[(size_t)(row % KQ) * D_MODEL + d]);
        v[i] = x;
    }
    float s = block_reduce_sum_f(v[0] + v[1] + v[2], red);
    float mean = s * (1.f / D_MODEL);
    float d0 = v[0] - mean, d1 = v[1] - mean, d2 = v[2] - mean;
    float sq = block_reduce_sum_f(d0 * d0 + d1 * d1 + d2 * d2, red);
    float rstd = rsqrtf(sq * (1.f / D_MODEL) + 1e-5f);
#pragma unroll
    for (int i = 0; i < 3; i++) {
        int d = tid + i * 256;
        out[(size_t)row * D_MODEL + d] = f2bf((v[i] - mean) * rstd * g[d] + be[d]);
    }
}

// ---------------------------------------------------------------------------
// MFMA cross-attention, one block per (b,h), 4 waves; wave w owns query rows
// 32w..32w+31.  (unchanged from R3 — verified)
// ---------------------------------------------------------------------------
__global__ __launch_bounds__(256) void attn_mfma(
    const ushort_t* __restrict__ q, const ushort_t* __restrict__ k,
    const ushort_t* __restrict__ v, ushort_t* __restrict__ ctx)
{
    __shared__ ushort_t Pt[128][72];
    __shared__ ushort_t Vt[96][72];

    const int bh = blockIdx.x;
    const int b = bh >> 3, h = bh & 7;
    const int tid = threadIdx.x;
    const int w = tid >> 6, lane = tid & 63;
    const int quad = lane >> 4, l16 = lane & 15;
    const int mrow0 = 32 * w;

    for (int idx = tid; idx < 96 * 64; idx += 256) {
        int d = idx >> 6, s = idx & 63;
        ushort_t val = 0;
        if (s < SEQ) val = v[(size_t)(b * SEQ + s) * D_MODEL + h * HDIM + d];
        Vt[d][s] = val;
    }

    f32x4 accS[2][4];
#pragma unroll
    for (int i = 0; i < 2; i++)
#pragma unroll
        for (int j = 0; j < 4; j++) accS[i][j] = (f32x4){0.f, 0.f, 0.f, 0.f};

#pragma unroll
    for (int k0 = 0; k0 < HDIM; k0 += 32) {
        short8 af[2], bfr[4];
#pragma unroll
        for (int mt = 0; mt < 2; mt++) {
            int kq = min(mrow0 + mt * 16 + l16, KQ - 1);
            af[mt] = *(const short8*)(q + (size_t)kq * D_MODEL + h * HDIM + k0 + quad * 8);
        }
#pragma unroll
        for (int nt = 0; nt < 4; nt++) {
            int s = min(nt * 16 + l16, SEQ - 1);
            bfr[nt] = *(const short8*)(k + (size_t)(b * SEQ + s) * D_MODEL + h * HDIM + k0 + quad * 8);
        }
#pragma unroll
        for (int mt = 0; mt < 2; mt++)
#pragma unroll
            for (int nt = 0; nt < 4; nt++)
                accS[mt][nt] = __builtin_amdgcn_mfma_f32_16x16x32_bf16(
                    af[mt], bfr[nt], accS[mt][nt], 0, 0, 0);
    }

#pragma unroll
    for (int mt = 0; mt < 2; mt++) {
#pragma unroll
        for (int r = 0; r < 4; r++) {
            float vals[4];
            float vmax = -1e30f;
#pragma unroll
            for (int nt = 0; nt < 4; nt++) {
                vals[nt] = accS[mt][nt][r];
                if (nt * 16 + l16 < SEQ) vmax = fmaxf(vmax, vals[nt]);
            }
#pragma unroll
            for (int off = 1; off < 16; off <<= 1)
                vmax = fmaxf(vmax, __shfl_xor(vmax, off));
            float p[4], psum = 0.f;
#pragma unroll
            for (int nt = 0; nt < 4; nt++) {
                float e = (nt * 16 + l16 < SEQ) ? __expf(vals[nt] - vmax) : 0.f;
                p[nt] = e;
                psum += e;
            }
#pragma unroll
            for (int off = 1; off < 16; off <<= 1)
                psum += __shfl_xor(psum, off);
            const float inv = 1.f / psum;
            const int row = mrow0 + mt * 16 + quad * 4 + r;
#pragma unroll
            for (int nt = 0; nt < 4; nt++)
                Pt[row][nt * 16 + l16] = f2bf(p[nt] * inv);
        }
    }
    __syncthreads();

    f32x4 accO[2][6];
#pragma unroll
    for (int i = 0; i < 2; i++)
#pragma unroll
        for (int j = 0; j < 6; j++) accO[i][j] = (f32x4){0.f, 0.f, 0.f, 0.f};

#pragma unroll
    for (int k0 = 0; k0 < 64; k0 += 32) {
        short8 af[2], bfr[6];
#pragma unroll
        for (int mt = 0; mt < 2; mt++)
            af[mt] = *(const short8*)(&Pt[mrow0 + mt * 16 + l16][k0 + quad * 8]);
#pragma unroll
        for (int nt = 0; nt < 6; nt++)
            bfr[nt] = *(const short8*)(&Vt[nt * 16 + l16][k0 + quad * 8]);
#pragma unroll
        for (int mt = 0; mt < 2; mt++)
#pragma unroll
            for (int nt = 0; nt < 6; nt++)
                accO[mt][nt] = __builtin_amdgcn_mfma_f32_16x16x32_bf16(
                    af[mt], bfr[nt], accO[mt][nt], 0, 0, 0);
    }

#pragma unroll
    for (int mt = 0; mt < 2; mt++) {
#pragma unroll
        for (int r = 0; r < 4; r++) {
            const int kq = mrow0 + mt * 16 + quad * 4 + r;
            if (kq < KQ) {
                size_t oa = (size_t)(b * KQ + kq) * D_MODEL + h * HDIM;
#pragma unroll
                for (int nt = 0; nt < 6; nt++)
                    ctx[oa + nt * 16 + l16] = f2bf(accO[mt][nt][r]);
            }
        }
    }
}

// ---------------------------------------------------------------------------
// GroupFC v2: block = (bgroup of 8 batches, kq).  dup_pool slab [768][10]
// staged once in LDS (pad 11 -> conflict-free), reused by 8 batch rows.
// logits[b, kq*10+g] = h[b,kq,:] . dp[kq,:,g] + db[kq*10+g]
// ---------------------------------------------------------------------------
__global__ __launch_bounds__(256) void groupfc2(
    const ushort_t* __restrict__ h, const float* __restrict__ dp,
    const float* __restrict__ dbias, float* __restrict__ out)
{
    __shared__ float dps[D_MODEL * 11];   // [d][g] padded
    __shared__ float hsr[8][D_MODEL];

    const int b0 = blockIdx.x * 8;
    const int kq = blockIdx.y;
    const int tid = threadIdx.x;

    for (int i = tid; i < D_MODEL * GRP; i += 256) {
        int d = i / GRP, g = i - d * GRP;
        dps[d * 11 + g] = dp[(size_t)kq * (D_MODEL * GRP) + i];
    }
#pragma unroll
    for (int bb = 0; bb < 8; bb++) {
#pragma unroll
        for (int i = 0; i < 3; i++) {
            int d = tid + i * 256;
            hsr[bb][d] = bf2f(h[(size_t)((b0 + bb) * KQ + kq) * D_MODEL + d]);
        }
    }
    __syncthreads();

    const int w = tid >> 6, lane = tid & 63;
    for (int item = w; item < 8 * GRP; item += 4) {
        int bb = item / GRP, g = item - bb * GRP;
        float a = 0.f;
#pragma unroll
        for (int i = 0; i < 12; i++) {
            int d = lane + i * 64;
            a = fmaf(hsr[bb][d], dps[d * 11 + g], a);
        }
#pragma unroll
        for (int off = 32; off > 0; off >>= 1) a += __shfl_down(a, off);
        if (lane == 0)
            out[(size_t)(b0 + bb) * NCLS + kq * GRP + g] = a + dbias[kq * GRP + g];
    }
}

// ---------------------------------------------------------------------------
extern "C" void kernel_launch(void* const* d_in, const int* in_sizes, int n_in,
                              void* d_out, int out_size, void* d_ws, size_t ws_size,
                              hipStream_t stream)
{
    const float* x   = (const float*)d_in[0];
    const float* We  = (const float*)d_in[1];
    const float* be_ = (const float*)d_in[2];
    const float* qe  = (const float*)d_in[3];
    const float* wq  = (const float*)d_in[4];
    const float* wk  = (const float*)d_in[5];
    const float* wv  = (const float*)d_in[6];
    const float* bq  = (const float*)d_in[7];
    const float* bk  = (const float*)d_in[8];
    const float* bv  = (const float*)d_in[9];
    const float* wo  = (const float*)d_in[10];
    const float* bo  = (const float*)d_in[11];
    const float* w1  = (const float*)d_in[12];
    const float* b1  = (const float*)d_in[13];
    const float* w2  = (const float*)d_in[14];
    const float* b2  = (const float*)d_in[15];
    const float* g1  = (const float*)d_in[16];
    const float* be1 = (const float*)d_in[17];
    const float* g2  = (const float*)d_in[18];
    const float* be2 = (const float*)d_in[19];
    const float* g3  = (const float*)d_in[20];
    const float* be3 = (const float*)d_in[21];
    const float* dp  = (const float*)d_in[22];
    const float* db  = (const float*)d_in[23];
    float* out = (float*)d_out;
    ushort_t* ws = (ushort_t*)d_ws;

    // Workspace (bf16 elems). Region A [0, 27,295,744) time-shared:
    //   phase1: xb | mem | kb | vb     phase2 (>= ffn1): ffh (26,214,400)
    ushort_t* xb  = ws;                      // 6272*2048 = 12,845,056
    ushort_t* mem = xb + 12845056;           // 6272*768  =  4,816,896
    ushort_t* kb  = mem + 4816896;
    ushort_t* vb  = kb + 4816896;
    ushort_t* ffh = ws;                      // 12800*2048 = 26,214,400 (phase2)
    ushort_t* rB  = ws + 27295744;
    ushort_t* Wet = rB;                      // 768*2048 = 1,572,864
    ushort_t* wqt = Wet + 1572864;           // 768*768  =   589,824
    ushort_t* wkt = wqt + 589824;            // wkt/wvt adjacent -> fused kv GEMM
    ushort_t* wvt = wkt + 589824;
    ushort_t* wot = wvt + 589824;
    ushort_t* w1t = wot + 589824;            // 2048*768 = 1,572,864
    ushort_t* w2t = w1t + 1572864;           // 768*2048 = 1,572,864
    ushort_t* tgt = w2t + 1572864;           // 100*768 = 76,800
    ushort_t* qb  = tgt + 76800;
    ushort_t* ctx = qb + 76800;              // 12800*768 = 9,830,400
    ushort_t* t2  = ctx + 9830400;
    ushort_t* hb  = t2 + 9830400;

    dim3 blk(256);
    const float qscale = 1.0f / sqrtf((float)HDIM);

    // --- conversions (2 dispatches) ---
    x_conv<<<dim3(8, NB), blk, 0, stream>>>(x, xb);
    wt_conv_all<<<dim3(1728), blk, 0, stream>>>(We, wq, wk, wv, wo, w1, w2,
                                                Wet, wqt, wkt, wvt, wot, w1t, w2t);

    // --- pipeline ---
    // 1. mem = relu(xb @ We + b_embed)   [6272 x 768, K=2048]  MT=2 -> 588 blocks
    gemm_bf16<2><<<dim3(6, 98), blk, 0, stream>>>(xb, Wet, be_, be_, mem, mem,
                                                  6272, 768, 2048, 768, 1, 1.f);
    // 2. tgt = LN(2*qe)
    ln_fused<<<dim3(KQ), blk, 0, stream>>>(qe, 0, nullptr, 0, g1, be1, tgt, 2.0f);
    // 3. qb = (tgt@wq + bq)/sqrt(96)     [100 x 768, K=768]
    gemm_bf16<4><<<dim3(6, 1), blk, 0, stream>>>(tgt, wqt, bq, bq, qb, qb,
                                                 KQ, 768, 768, 768, 0, qscale);
    // 4. fused k|v                       [6272 x 1536, K=768], split at 768
    gemm_bf16<4><<<dim3(12, 49), blk, 0, stream>>>(mem, wkt, bk, bv, kb, vb,
                                                   6272, 1536, 768, 768, 0, 1.f);
    // 5. attention -> ctx
    attn_mfma<<<dim3(NB * HEADS), blk, 0, stream>>>(qb, kb, vb, ctx);
    // 6. t2 = ctx@wo + bo                [12800 x 768, K=768]
    gemm_bf16<4><<<dim3(6, 100), blk, 0, stream>>>(ctx, wot, bo, bo, t2, t2,
                                                   12800, 768, 768, 768, 0, 1.f);
    // 7. t2 = LN(t2 + bcast tgt)
    ln_fused<<<dim3(12800), blk, 0, stream>>>(t2, 1, tgt, 2, g2, be2, t2, 1.0f);
    // 8. ffh = relu(t2@w1 + b1)          [12800 x 2048, K=768]
    gemm_bf16<4><<<dim3(16, 100), blk, 0, stream>>>(t2, w1t, b1, b1, ffh, ffh,
                                                    12800, 2048, 768, 2048, 1, 1.f);
    // 9. hb = ffh@w2 + b2                [12800 x 768, K=2048]
    gemm_bf16<4><<<dim3(6, 100), blk, 0, stream>>>(ffh, w2t, b2, b2, hb, hb,
                                                   12800, 768, 2048, 768, 0, 1.f);
    // 10. hb = LN(hb + t2)
    ln_fused<<<dim3(12800), blk, 0, stream>>>(hb, 1, t2, 1, g3, be3, hb, 1.0f);
    // 11. GroupFC -> out (fp32 logits)
    groupfc2<<<dim3(16, KQ), blk, 0, stream>>>(hb, dp, db, out);
}